// Round 3
// baseline (208.129 us; speedup 1.0000x reference)
//
#include <hip/hip_runtime.h>

#define NB 4
#define NS 2048
#define ND 768
#define NH 12
#define NDH 64
#define XPITCH 72
#define SSCALE 0.18033688011112043f   // (1/sqrt(64)) * log2(e)

typedef __bf16 bf16x8 __attribute__((ext_vector_type(8)));
typedef __bf16 bf16x4 __attribute__((ext_vector_type(4)));
typedef float  f32x4  __attribute__((ext_vector_type(4)));
typedef unsigned int u32;

#define MFMA16(a, b, c) __builtin_amdgcn_mfma_f32_16x16x32_bf16(a, b, c, 0, 0, 0)

// pack two floats -> two bf16 (round-half-up) in one v_perm_b32
__device__ __forceinline__ u32 packbf(float a, float b) {
    u32 ua = __builtin_bit_cast(u32, a) + 0x8000u;
    u32 ub = __builtin_bit_cast(u32, b) + 0x8000u;
    return __builtin_amdgcn_perm(ub, ua, 0x07060302u);
}

__device__ __forceinline__ bf16x8 cvt8(float4 a, float4 b) {
    union { u32 u[4]; bf16x8 v; } r;
    r.u[0] = packbf(a.x, a.y); r.u[1] = packbf(a.z, a.w);
    r.u[2] = packbf(b.x, b.y); r.u[3] = packbf(b.z, b.w);
    return r.v;
}

__device__ __forceinline__ __bf16 f2bf(float f) {
    u32 u = __builtin_bit_cast(u32, f) + 0x8000u;
    unsigned short s = (unsigned short)(u >> 16);
    return __builtin_bit_cast(__bf16, s);
}

// async global->LDS DMA, 16B per lane (dest = wave-uniform base + lane*16)
__device__ __forceinline__ void gld16(const __bf16* g, __bf16* l) {
    __builtin_amdgcn_global_load_lds(
        (const __attribute__((address_space(1))) u32*)g,
        (__attribute__((address_space(3))) u32*)l, 16, 0, 0);
}

// ---------------------------------------------------------------------------
// Kernel 1: QKV projections, all computed TRANSPOSED (M = e) so the C-layout
// rows are e-contiguous per lane; outputs transposed back through LDS slabs
// and stored with coalesced dwordx4.
//   qws, kws: [b*H+h][s][64] bf16 (Q pre-scaled by SSCALE)
//   vtws:     [b*H+h][e][S]  bf16 with within-32 column perm:
//             pos(k32) = ((k32>>2)&3)*8 + (k32>>4)*4 + (k32&3)
// Weights read as A-fragments straight from global fp32 (L2-hot, no LDS).
// ---------------------------------------------------------------------------
__global__ __launch_bounds__(256, 4) void proj_kernel(
    const float* __restrict__ x,
    const float* __restrict__ wq, const float* __restrict__ bq,
    const float* __restrict__ wk, const float* __restrict__ bk,
    const float* __restrict__ wv, const float* __restrict__ bv,
    __bf16* __restrict__ qws, __bf16* __restrict__ kws, __bf16* __restrict__ vtws)
{
    const int st = blockIdx.x, h = blockIdx.y, b = blockIdx.z;
    const int s0 = st * 64;
    const int tid = threadIdx.x;

    __shared__ __align__(16) __bf16 Xs[64 * XPITCH];
    __shared__ __align__(16) __bf16 Tq[64 * XPITCH];
    __shared__ __align__(16) __bf16 Tk[64 * XPITCH];
    __shared__ __align__(16) __bf16 Tv[64 * XPITCH];

    const int r = tid >> 2, f = tid & 3;
    {   // stage X tile (64 s-rows x 64 d) fp32 -> bf16 LDS
        const float* xrow = x + (size_t)(b * NS + s0 + r) * ND + h * NDH + f * 16;
        float4 v0 = *(const float4*)(xrow);
        float4 v1 = *(const float4*)(xrow + 4);
        float4 v2 = *(const float4*)(xrow + 8);
        float4 v3 = *(const float4*)(xrow + 12);
        *(bf16x8*)&Xs[r * XPITCH + f * 16]     = cvt8(v0, v1);
        *(bf16x8*)&Xs[r * XPITCH + f * 16 + 8] = cvt8(v2, v3);
    }

    const int lane = tid & 63, w = tid >> 6, col = lane & 15, quad = lane >> 4;

    // weight A-fragments from global fp32 (rows e = w*16+col)
    const size_t wrow = (size_t)(h * NDH + w * 16 + col) * NDH;
    const float* wq0 = wq + wrow + quad * 8;
    const float* wk0 = wk + wrow + quad * 8;
    const float* wv0 = wv + wrow + quad * 8;
    bf16x8 wqa0 = cvt8(*(const float4*)(wq0),      *(const float4*)(wq0 + 4));
    bf16x8 wqa1 = cvt8(*(const float4*)(wq0 + 32), *(const float4*)(wq0 + 36));
    bf16x8 wka0 = cvt8(*(const float4*)(wk0),      *(const float4*)(wk0 + 4));
    bf16x8 wka1 = cvt8(*(const float4*)(wk0 + 32), *(const float4*)(wk0 + 36));
    bf16x8 wva0 = cvt8(*(const float4*)(wv0),      *(const float4*)(wv0 + 4));
    bf16x8 wva1 = cvt8(*(const float4*)(wv0 + 32), *(const float4*)(wv0 + 36));

    float bqs[4], bks[4], bvs[4];
#pragma unroll
    for (int rr = 0; rr < 4; ++rr) {
        const int e = h * NDH + w * 16 + quad * 4 + rr;
        bqs[rr] = bq[e] * SSCALE;
        bks[rr] = bk[e];
        bvs[rr] = bv[e];
    }

    __syncthreads();

    // X B-fragments (rows s = nt*16+col) — shared by Q,K,V
    bf16x8 xb0[4], xb1[4];
#pragma unroll
    for (int nt = 0; nt < 4; ++nt) {
        xb0[nt] = *(const bf16x8*)&Xs[(nt * 16 + col) * XPITCH + quad * 8];
        xb1[nt] = *(const bf16x8*)&Xs[(nt * 16 + col) * XPITCH + 32 + quad * 8];
    }

#pragma unroll
    for (int nt = 0; nt < 4; ++nt) {
        f32x4 aq = {0.f, 0.f, 0.f, 0.f};
        f32x4 ak = {0.f, 0.f, 0.f, 0.f};
        f32x4 av = {0.f, 0.f, 0.f, 0.f};
        aq = MFMA16(wqa0, xb0[nt], aq); aq = MFMA16(wqa1, xb1[nt], aq);
        ak = MFMA16(wka0, xb0[nt], ak); ak = MFMA16(wka1, xb1[nt], ak);
        av = MFMA16(wva0, xb0[nt], av); av = MFMA16(wva1, xb1[nt], av);

        // Q (scaled), K: lane holds 4 e-contiguous values -> b64 into slab[s][e]
        union { u32 u[2]; uint2 v; } pq, pk;
        pq.u[0] = packbf(fmaf(aq[0], SSCALE, bqs[0]), fmaf(aq[1], SSCALE, bqs[1]));
        pq.u[1] = packbf(fmaf(aq[2], SSCALE, bqs[2]), fmaf(aq[3], SSCALE, bqs[3]));
        pk.u[0] = packbf(ak[0] + bks[0], ak[1] + bks[1]);
        pk.u[1] = packbf(ak[2] + bks[2], ak[3] + bks[3]);
        const int soff = (nt * 16 + col) * XPITCH + w * 16 + quad * 4;
        *(uint2*)&Tq[soff] = pq.v;
        *(uint2*)&Tk[soff] = pk.v;

        // V: scalar b16 into slab[e][pos] with within-32 column perm
        const int pos = ((nt >> 1) << 5) + ((col >> 2) << 3) + ((nt & 1) << 2) + (col & 3);
#pragma unroll
        for (int rr = 0; rr < 4; ++rr)
            Tv[(w * 16 + quad * 4 + rr) * XPITCH + pos] = f2bf(av[rr] + bvs[rr]);
    }
    __syncthreads();

    // coalesced writeback
    const size_t bh = (size_t)(b * NH + h);
    {
        const uint4 a0 = *(const uint4*)&Tq[r * XPITCH + f * 16];
        const uint4 a1 = *(const uint4*)&Tq[r * XPITCH + f * 16 + 8];
        __bf16* qdst = qws + (bh * NS + s0 + r) * NDH + f * 16;
        *(uint4*)qdst = a0; *(uint4*)(qdst + 8) = a1;

        const uint4 k0 = *(const uint4*)&Tk[r * XPITCH + f * 16];
        const uint4 k1 = *(const uint4*)&Tk[r * XPITCH + f * 16 + 8];
        __bf16* kdst = kws + (bh * NS + s0 + r) * NDH + f * 16;
        *(uint4*)kdst = k0; *(uint4*)(kdst + 8) = k1;

        const uint4 v0 = *(const uint4*)&Tv[r * XPITCH + f * 16];
        const uint4 v1 = *(const uint4*)&Tv[r * XPITCH + f * 16 + 8];
        __bf16* vdst = vtws + (bh * NDH + r) * NS + s0 + f * 16;   // row = e
        *(uint4*)vdst = v0; *(uint4*)(vdst + 8) = v1;
    }
}

// ---------------------------------------------------------------------------
// Kernel 2: flash attention, S^T formulation + split-K across waves.
// Super-tiles of 128 k; wave w owns k-slice [w*32, w*32+32). Wave-private
// online-softmax state (m,l per q) and O^T accumulator; FA split-K combine
// at block end via LDS. K/Vt staged by global_load_lds DMA with XOR chunk
// swizzle (conflict-free, no pads, no ds_writes). Q fragments in registers.
// ---------------------------------------------------------------------------
__global__ __launch_bounds__(256, 3) void attn_kernel(
    const __bf16* __restrict__ qws, const __bf16* __restrict__ kws,
    const __bf16* __restrict__ vtws, float* __restrict__ out)
{
    const int qt = blockIdx.x, h = blockIdx.y, b = blockIdx.z;
    const int q0 = qt * 64;
    const int tid = threadIdx.x;

    __shared__ __align__(16) unsigned char smem[36864];
    __bf16* Ks  = (__bf16*)smem;                 // 128 rows x 64, swizzled chunks
    __bf16* Vts = (__bf16*)(smem + 16384);       // 64 rows x 128, swizzled chunks
    float* slabA = (float*)smem;                 // 64 x 68 f32 (aliases Ks+)
    float* slabB = (float*)(smem + 17408);       // 64 x 68 f32
    float* mbuf  = (float*)(smem + 34816);       // 256 f32
    float* lbuf  = mbuf + 256;                   // 256 f32

    const size_t bh = (size_t)(b * NH + h);
    const int lane = tid & 63, w = tid >> 6, col = lane & 15, quad = lane >> 4;

    // Q B-fragments straight from global (rows q = q0+nt*16+col)
    bf16x8 qb0[4], qb1[4];
#pragma unroll
    for (int nt = 0; nt < 4; ++nt) {
        const __bf16* qp = qws + (bh * NS + q0 + nt * 16 + col) * NDH + quad * 8;
        qb0[nt] = *(const bf16x8*)(qp);
        qb1[nt] = *(const bf16x8*)(qp + 32);
    }

    // DMA source addressing (XOR swizzle: stored chunk qs = data chunk qd ^ (row&7))
    const int rK = tid >> 3;                       // K row (per i: + i*32)
    const int qdK = (tid & 7) ^ (rK & 7);
    const __bf16* ksrc = kws + bh * (size_t)NS * NDH + rK * NDH + qdK * 8;
    const int rV = tid >> 4;                       // V row (per i: + i*16)
    const int qdV = (tid & 15) ^ (rV & 7);
    const __bf16* vsrc = vtws + (bh * (size_t)NDH + rV) * NS + qdV * 8;
    __bf16* kdst = Ks  + tid * 8;
    __bf16* vdst = Vts + tid * 8;

    // loop-invariant LDS read offsets (swizzled)
    const int cx7 = col & 7;
    int ka_off[2][2], va_off[4];
#pragma unroll
    for (int mt = 0; mt < 2; ++mt) {
        const int rr = w * 32 + mt * 16 + col;
        ka_off[mt][0] = rr * 64 + ((quad)     ^ cx7) * 8;
        ka_off[mt][1] = rr * 64 + ((quad + 4) ^ cx7) * 8;
    }
#pragma unroll
    for (int dt = 0; dt < 4; ++dt) {
        const int rr = dt * 16 + col;
        va_off[dt] = rr * 128 + ((w * 4 + quad) ^ cx7) * 8;
    }

    float m[4], l[4];
#pragma unroll
    for (int nt = 0; nt < 4; ++nt) { m[nt] = -__builtin_inff(); l[nt] = 0.f; }
    f32x4 o[4][4];
#pragma unroll
    for (int dt = 0; dt < 4; ++dt)
#pragma unroll
        for (int nt = 0; nt < 4; ++nt) o[dt][nt] = (f32x4){0.f, 0.f, 0.f, 0.f};

    for (int kt = 0; kt < NS / 128; ++kt) {
        __syncthreads();                            // prev tile consumers done
#pragma unroll
        for (int i = 0; i < 4; ++i)
            gld16(ksrc + (size_t)kt * 8192 + i * 2048, kdst + i * 2048);
#pragma unroll
        for (int i = 0; i < 4; ++i)
            gld16(vsrc + kt * 128 + i * 32768, vdst + i * 2048);
        __syncthreads();                            // DMA drained (vmcnt before barrier)

        bf16x8 ka[2][2], va[4];
#pragma unroll
        for (int mt = 0; mt < 2; ++mt) {
            ka[mt][0] = *(const bf16x8*)&Ks[ka_off[mt][0]];
            ka[mt][1] = *(const bf16x8*)&Ks[ka_off[mt][1]];
        }
#pragma unroll
        for (int dt = 0; dt < 4; ++dt) va[dt] = *(const bf16x8*)&Vts[va_off[dt]];

#pragma unroll
        for (int nt = 0; nt < 4; ++nt) {
            f32x4 sA = {0.f, 0.f, 0.f, 0.f};
            f32x4 sB = {0.f, 0.f, 0.f, 0.f};
            sA = MFMA16(ka[0][0], qb0[nt], sA); sA = MFMA16(ka[0][1], qb1[nt], sA);
            sB = MFMA16(ka[1][0], qb0[nt], sB); sB = MFMA16(ka[1][1], qb1[nt], sB);
            // lane holds k_local = mt*16 + quad*4 + r for q = nt*16+col (log2 domain)

            float rowm = fmaxf(fmaxf(fmaxf(sA[0], sA[1]), fmaxf(sA[2], sA[3])),
                               fmaxf(fmaxf(sB[0], sB[1]), fmaxf(sB[2], sB[3])));
            rowm = fmaxf(rowm, __shfl_xor(rowm, 16, 64));
            rowm = fmaxf(rowm, __shfl_xor(rowm, 32, 64));

            const float mn = fmaxf(m[nt], rowm);
            const float al = __builtin_amdgcn_exp2f(m[nt] - mn);   // 0 on first tile
            m[nt] = mn;

            const float p0 = __builtin_amdgcn_exp2f(sA[0] - mn);
            const float p1 = __builtin_amdgcn_exp2f(sA[1] - mn);
            const float p2 = __builtin_amdgcn_exp2f(sA[2] - mn);
            const float p3 = __builtin_amdgcn_exp2f(sA[3] - mn);
            const float p4 = __builtin_amdgcn_exp2f(sB[0] - mn);
            const float p5 = __builtin_amdgcn_exp2f(sB[1] - mn);
            const float p6 = __builtin_amdgcn_exp2f(sB[2] - mn);
            const float p7 = __builtin_amdgcn_exp2f(sB[3] - mn);
            float rs = ((p0 + p1) + (p2 + p3)) + ((p4 + p5) + (p6 + p7));
            rs += __shfl_xor(rs, 16, 64);
            rs += __shfl_xor(rs, 32, 64);
            l[nt] = l[nt] * al + rs;

            union { u32 u[4]; bf16x8 v; } pb;      // B-frag: k_mfma = quad*8 + mt*4 + r
            pb.u[0] = packbf(p0, p1);
            pb.u[1] = packbf(p2, p3);
            pb.u[2] = packbf(p4, p5);
            pb.u[3] = packbf(p6, p7);

#pragma unroll
            for (int dt = 0; dt < 4; ++dt) {
                o[dt][nt] *= al;
                o[dt][nt] = MFMA16(va[dt], pb.v, o[dt][nt]);
            }
        }
    }

    // ---- split-K combine across the 4 waves ----
    __syncthreads();
    if (quad == 0) {
#pragma unroll
        for (int nt = 0; nt < 4; ++nt) {
            mbuf[w * 64 + nt * 16 + col] = m[nt];
            lbuf[w * 64 + nt * 16 + col] = l[nt];
        }
    }
    __syncthreads();

    float scale[4];
#pragma unroll
    for (int nt = 0; nt < 4; ++nt) {
        const int qi = nt * 16 + col;
        const float m0 = mbuf[qi], m1 = mbuf[64 + qi], m2 = mbuf[128 + qi], m3 = mbuf[192 + qi];
        const float M = fmaxf(fmaxf(m0, m1), fmaxf(m2, m3));
        const float L = lbuf[qi]       * __builtin_amdgcn_exp2f(m0 - M)
                      + lbuf[64 + qi]  * __builtin_amdgcn_exp2f(m1 - M)
                      + lbuf[128 + qi] * __builtin_amdgcn_exp2f(m2 - M)
                      + lbuf[192 + qi] * __builtin_amdgcn_exp2f(m3 - M);
        scale[nt] = __builtin_amdgcn_exp2f(m[nt] - M) / L;
    }
#pragma unroll
    for (int dt = 0; dt < 4; ++dt)
#pragma unroll
        for (int nt = 0; nt < 4; ++nt) o[dt][nt] *= scale[nt];

    // waves 0,2 write slabs; waves 1,3 accumulate; layout slab[q][d] pitch 68
    if (w == 0 || w == 2) {
        float* s = (w == 0) ? slabA : slabB;
#pragma unroll
        for (int dt = 0; dt < 4; ++dt)
#pragma unroll
            for (int nt = 0; nt < 4; ++nt)
                *(f32x4*)&s[(nt * 16 + col) * 68 + dt * 16 + quad * 4] = o[dt][nt];
    }
    __syncthreads();
    if (w == 1 || w == 3) {
        float* s = (w == 1) ? slabA : slabB;
#pragma unroll
        for (int dt = 0; dt < 4; ++dt)
#pragma unroll
            for (int nt = 0; nt < 4; ++nt) {
                f32x4* p = (f32x4*)&s[(nt * 16 + col) * 68 + dt * 16 + quad * 4];
                *p = *p + o[dt][nt];
            }
    }
    __syncthreads();

    // final coalesced store
    const int qr = tid >> 2, fq = tid & 3;
#pragma unroll
    for (int j = 0; j < 4; ++j) {
        const f32x4 a = *(const f32x4*)&slabA[qr * 68 + fq * 16 + j * 4];
        const f32x4 c = *(const f32x4*)&slabB[qr * 68 + fq * 16 + j * 4];
        *(f32x4*)&out[(size_t)(b * NS + q0 + qr) * ND + h * NDH + fq * 16 + j * 4] = a + c;
    }
}

extern "C" void kernel_launch(void* const* d_in, const int* in_sizes, int n_in,
                              void* d_out, int out_size, void* d_ws, size_t ws_size,
                              hipStream_t stream) {
    (void)in_sizes; (void)n_in; (void)out_size; (void)ws_size;
    const float* x  = (const float*)d_in[0];
    const float* wq = (const float*)d_in[1];
    const float* bq = (const float*)d_in[2];
    const float* wk = (const float*)d_in[3];
    const float* bk = (const float*)d_in[4];
    const float* wv = (const float*)d_in[5];
    const float* bv = (const float*)d_in[6];
    float* out = (float*)d_out;

    __bf16* qws  = (__bf16*)d_ws;
    __bf16* kws  = qws + (size_t)NB * NH * NS * NDH;
    __bf16* vtws = kws + (size_t)NB * NH * NS * NDH;

    dim3 grid(NS / 64, NH, NB);
    proj_kernel<<<grid, 256, 0, stream>>>(x, wq, bq, wk, bk, wv, bv, qws, kws, vtws);
    attn_kernel<<<grid, 256, 0, stream>>>(qws, kws, vtws, out);
}

// Round 4
// 195.475 us; speedup vs baseline: 1.0647x; 1.0647x over previous
//
#include <hip/hip_runtime.h>

#define NB 4
#define NS 2048
#define ND 768
#define NH 12
#define NDH 64
#define XPITCH 72
#define SSCALE 0.18033688011112043f   // (1/sqrt(64)) * log2(e)

typedef __bf16 bf16x8 __attribute__((ext_vector_type(8)));
typedef float  f32x4  __attribute__((ext_vector_type(4)));
typedef unsigned int u32;

#define MFMA16(a, b, c) __builtin_amdgcn_mfma_f32_16x16x32_bf16(a, b, c, 0, 0, 0)

__device__ __forceinline__ u32 packbf(float a, float b) {
    u32 ua = __builtin_bit_cast(u32, a) + 0x8000u;
    u32 ub = __builtin_bit_cast(u32, b) + 0x8000u;
    return __builtin_amdgcn_perm(ub, ua, 0x07060302u);
}

__device__ __forceinline__ bf16x8 cvt8(float4 a, float4 b) {
    union { u32 u[4]; bf16x8 v; } r;
    r.u[0] = packbf(a.x, a.y); r.u[1] = packbf(a.z, a.w);
    r.u[2] = packbf(b.x, b.y); r.u[3] = packbf(b.z, b.w);
    return r.v;
}

__device__ __forceinline__ __bf16 f2bf(float f) {
    u32 u = __builtin_bit_cast(u32, f) + 0x8000u;
    unsigned short s = (unsigned short)(u >> 16);
    return __builtin_bit_cast(__bf16, s);
}

// async global->LDS DMA, 16B/lane (dest = wave-uniform base + lane*16)
__device__ __forceinline__ void gld16(const __bf16* g, __bf16* l) {
    __builtin_amdgcn_global_load_lds(
        (const __attribute__((address_space(1))) u32*)g,
        (__attribute__((address_space(3))) u32*)l, 16, 0, 0);
}

// ---------------------------------------------------------------------------
// Kernel 1: QKV projections. Block = (128 s-rows, h, b): 2 subtiles of 64,
// weight fragments loaded ONCE (halves weight traffic vs 64-row blocks),
// X for subtile 1 register-prefetched during subtile 0's compute.
// All GEMMs computed transposed (M = e): lane holds 4 consecutive e for one s
//  -> Q,K stored DIRECT to global as uint2 (no LDS round trip).
//  V needs [e][s] layout + within-32 column perm -> transpose slab.
//   qws,kws: [b*H+h][s][64] bf16 (Q pre-scaled by SSCALE)
//   vtws:    [b*H+h][e][S]  bf16, perm pos(k32)=((k32>>2)&3)*8+(k32>>4)*4+(k32&3)
// ---------------------------------------------------------------------------
__global__ __launch_bounds__(256, 2) void proj_kernel(
    const float* __restrict__ x,
    const float* __restrict__ wq, const float* __restrict__ bq,
    const float* __restrict__ wk, const float* __restrict__ bk,
    const float* __restrict__ wv, const float* __restrict__ bv,
    __bf16* __restrict__ qws, __bf16* __restrict__ kws, __bf16* __restrict__ vtws)
{
    const int st = blockIdx.x, h = blockIdx.y, b = blockIdx.z;
    const int sbase = st * 128;
    const int tid = threadIdx.x;

    __shared__ __align__(16) __bf16 Xs[64 * XPITCH];
    __shared__ __align__(16) __bf16 Tv[64 * XPITCH];

    const int r = tid >> 2, f = tid & 3;
    const int lane = tid & 63, w = tid >> 6, col = lane & 15, quad = lane >> 4;

    // ---- weight fragments from global fp32 (L2-hot), once per block ----
    const size_t wrow = (size_t)(h * NDH + w * 16 + col) * NDH;
    const float* wq0 = wq + wrow + quad * 8;
    const float* wk0 = wk + wrow + quad * 8;
    const float* wv0 = wv + wrow + quad * 8;
    const bf16x8 wqa0 = cvt8(*(const float4*)(wq0),      *(const float4*)(wq0 + 4));
    const bf16x8 wqa1 = cvt8(*(const float4*)(wq0 + 32), *(const float4*)(wq0 + 36));
    const bf16x8 wka0 = cvt8(*(const float4*)(wk0),      *(const float4*)(wk0 + 4));
    const bf16x8 wka1 = cvt8(*(const float4*)(wk0 + 32), *(const float4*)(wk0 + 36));
    const bf16x8 wva0 = cvt8(*(const float4*)(wv0),      *(const float4*)(wv0 + 4));
    const bf16x8 wva1 = cvt8(*(const float4*)(wv0 + 32), *(const float4*)(wv0 + 36));

    float bqs[4], bks[4], bvs[4];
#pragma unroll
    for (int rr = 0; rr < 4; ++rr) {
        const int e = h * NDH + w * 16 + quad * 4 + rr;
        bqs[rr] = bq[e] * SSCALE;
        bks[rr] = bk[e];
        bvs[rr] = bv[e];
    }

    const size_t bh = (size_t)(b * NH + h);

    // ---- prologue: load X(subtile 0) into registers ----
    float4 xr[4];
    {
        const float* xrow = x + (size_t)(b * NS + sbase + r) * ND + h * NDH + f * 16;
        xr[0] = *(const float4*)(xrow);
        xr[1] = *(const float4*)(xrow + 4);
        xr[2] = *(const float4*)(xrow + 8);
        xr[3] = *(const float4*)(xrow + 12);
    }

    for (int sub = 0; sub < 2; ++sub) {
        const int s0 = sbase + sub * 64;

        // regs -> LDS (bf16)
        *(bf16x8*)&Xs[r * XPITCH + f * 16]     = cvt8(xr[0], xr[1]);
        *(bf16x8*)&Xs[r * XPITCH + f * 16 + 8] = cvt8(xr[2], xr[3]);
        __syncthreads();

        if (sub == 0) {   // prefetch X(subtile 1) while computing subtile 0
            const float* xrow = x + (size_t)(b * NS + sbase + 64 + r) * ND + h * NDH + f * 16;
            xr[0] = *(const float4*)(xrow);
            xr[1] = *(const float4*)(xrow + 4);
            xr[2] = *(const float4*)(xrow + 8);
            xr[3] = *(const float4*)(xrow + 12);
        }

        // X B-fragments (rows s = nt*16+col)
        bf16x8 xb0[4], xb1[4];
#pragma unroll
        for (int nt = 0; nt < 4; ++nt) {
            xb0[nt] = *(const bf16x8*)&Xs[(nt * 16 + col) * XPITCH + quad * 8];
            xb1[nt] = *(const bf16x8*)&Xs[(nt * 16 + col) * XPITCH + 32 + quad * 8];
        }

#pragma unroll
        for (int nt = 0; nt < 4; ++nt) {
            f32x4 aq = {0.f, 0.f, 0.f, 0.f};
            f32x4 ak = {0.f, 0.f, 0.f, 0.f};
            f32x4 av = {0.f, 0.f, 0.f, 0.f};
            aq = MFMA16(wqa0, xb0[nt], aq); aq = MFMA16(wqa1, xb1[nt], aq);
            ak = MFMA16(wka0, xb0[nt], ak); ak = MFMA16(wka1, xb1[nt], ak);
            av = MFMA16(wva0, xb0[nt], av); av = MFMA16(wva1, xb1[nt], av);

            // Q (scaled) and K: direct global uint2 store (4 e-contig bf16)
            union { u32 u[2]; uint2 v; } pq, pk;
            pq.u[0] = packbf(fmaf(aq[0], SSCALE, bqs[0]), fmaf(aq[1], SSCALE, bqs[1]));
            pq.u[1] = packbf(fmaf(aq[2], SSCALE, bqs[2]), fmaf(aq[3], SSCALE, bqs[3]));
            pk.u[0] = packbf(ak[0] + bks[0], ak[1] + bks[1]);
            pk.u[1] = packbf(ak[2] + bks[2], ak[3] + bks[3]);
            const size_t goff = (bh * NS + s0 + nt * 16 + col) * NDH + w * 16 + quad * 4;
            *(uint2*)(qws + goff) = pq.v;
            *(uint2*)(kws + goff) = pk.v;

            // V: transpose slab [e][pos], within-32 column perm
            const int pos = ((nt >> 1) << 5) + ((col >> 2) << 3) + ((nt & 1) << 2) + (col & 3);
#pragma unroll
            for (int rr = 0; rr < 4; ++rr)
                Tv[(w * 16 + quad * 4 + rr) * XPITCH + pos] = f2bf(av[rr] + bvs[rr]);
        }
        __syncthreads();

        // coalesced V writeback (row = e)
        {
            const uint4 v0 = *(const uint4*)&Tv[r * XPITCH + f * 16];
            const uint4 v1 = *(const uint4*)&Tv[r * XPITCH + f * 16 + 8];
            __bf16* vdst = vtws + (bh * NDH + r) * NS + s0 + f * 16;
            *(uint4*)vdst = v0; *(uint4*)(vdst + 8) = v1;
        }
        __syncthreads();   // Tv / Xs safe to overwrite next subtile
    }
}

// ---------------------------------------------------------------------------
// Kernel 2: flash attention, S^T formulation + split-K across waves +
// DOUBLE-BUFFERED DMA staging (m97 structure): DMA for super-tile t+1 issued
// at top of iter t, consumed next iter -> full compute phase of load slack.
// Wave w owns k-slice [w*32,w*32+32) of each 128-k super-tile; wave-private
// (m,l,O); FA split-K combine at end via LDS. XOR chunk swizzle keeps all
// LDS accesses conflict-free with zero padding.
// ---------------------------------------------------------------------------
__global__ __launch_bounds__(256, 2) void attn_kernel(
    const __bf16* __restrict__ qws, const __bf16* __restrict__ kws,
    const __bf16* __restrict__ vtws, float* __restrict__ out)
{
    const int qt = blockIdx.x, h = blockIdx.y, b = blockIdx.z;
    const int q0 = qt * 64;
    const int tid = threadIdx.x;

    // buf b: K at b*32KB, V at b*32KB+16KB. Epilogue slabs alias buf0.
    __shared__ __align__(16) unsigned char smem[65536];
    __bf16* lds = (__bf16*)smem;
    float* slabA = (float*)smem;                 // 64 x 68 f32
    float* slabB = (float*)(smem + 17408);       // 64 x 68 f32
    float* mbuf  = (float*)(smem + 34816);       // 256 f32
    float* lbuf  = mbuf + 256;                   // 256 f32

    const size_t bh = (size_t)(b * NH + h);
    const int lane = tid & 63, w = tid >> 6, col = lane & 15, quad = lane >> 4;

    // Q B-fragments straight from global (rows q = q0+nt*16+col)
    bf16x8 qb0[4], qb1[4];
#pragma unroll
    for (int nt = 0; nt < 4; ++nt) {
        const __bf16* qp = qws + (bh * NS + q0 + nt * 16 + col) * NDH + quad * 8;
        qb0[nt] = *(const bf16x8*)(qp);
        qb1[nt] = *(const bf16x8*)(qp + 32);
    }

    // DMA source addressing (XOR swizzle: stored chunk = data chunk ^ (row&7))
    const int rK = tid >> 3;
    const int qdK = (tid & 7) ^ (rK & 7);
    const __bf16* ksrc = kws + bh * (size_t)NS * NDH + rK * NDH + qdK * 8;
    const int rV = tid >> 4;
    const int qdV = (tid & 15) ^ (rV & 7);
    const __bf16* vsrc = vtws + (bh * (size_t)NDH + rV) * NS + qdV * 8;

    // loop-invariant swizzled LDS read offsets (relative to buffer base, elems)
    const int cx7 = col & 7;
    int ka_off[2][2], va_off[4];
#pragma unroll
    for (int mt = 0; mt < 2; ++mt) {
        const int rr = w * 32 + mt * 16 + col;
        ka_off[mt][0] = rr * 64 + ((quad)     ^ cx7) * 8;
        ka_off[mt][1] = rr * 64 + ((quad + 4) ^ cx7) * 8;
    }
#pragma unroll
    for (int dt = 0; dt < 4; ++dt) {
        const int rr = dt * 16 + col;
        va_off[dt] = 8192 + rr * 128 + ((w * 4 + quad) ^ cx7) * 8;
    }

    float m[4], l[4];
#pragma unroll
    for (int nt = 0; nt < 4; ++nt) { m[nt] = -__builtin_inff(); l[nt] = 0.f; }
    f32x4 o[4][4];
#pragma unroll
    for (int dt = 0; dt < 4; ++dt)
#pragma unroll
        for (int nt = 0; nt < 4; ++nt) o[dt][nt] = (f32x4){0.f, 0.f, 0.f, 0.f};

    // prologue: DMA super-tile 0 into buf0
    {
        __bf16* kdst = lds + tid * 8;
        __bf16* vdst = lds + 8192 + tid * 8;
#pragma unroll
        for (int i = 0; i < 4; ++i) gld16(ksrc + i * 2048, kdst + i * 2048);
#pragma unroll
        for (int i = 0; i < 4; ++i) gld16(vsrc + i * 32768, vdst + i * 2048);
    }
    __syncthreads();   // drain tile-0 DMA (also covers qb loads)

    for (int kt = 0; kt < NS / 128; ++kt) {
        const int cur = (kt & 1) * 16384;
        if (kt + 1 < NS / 128) {   // issue DMA for next tile into other buffer
            const int nxt = ((kt + 1) & 1) * 16384;
            __bf16* kdst = lds + nxt + tid * 8;
            __bf16* vdst = lds + nxt + 8192 + tid * 8;
            const __bf16* ks = ksrc + (size_t)(kt + 1) * 8192;
            const __bf16* vs = vsrc + (kt + 1) * 128;
#pragma unroll
            for (int i = 0; i < 4; ++i) gld16(ks + i * 2048, kdst + i * 2048);
#pragma unroll
            for (int i = 0; i < 4; ++i) gld16(vs + i * 32768, vdst + i * 2048);
        }

        bf16x8 ka[2][2], va[4];
#pragma unroll
        for (int mt = 0; mt < 2; ++mt) {
            ka[mt][0] = *(const bf16x8*)&lds[cur + ka_off[mt][0]];
            ka[mt][1] = *(const bf16x8*)&lds[cur + ka_off[mt][1]];
        }
#pragma unroll
        for (int dt = 0; dt < 4; ++dt) va[dt] = *(const bf16x8*)&lds[cur + va_off[dt]];

#pragma unroll
        for (int nt = 0; nt < 4; ++nt) {
            f32x4 sA = {0.f, 0.f, 0.f, 0.f};
            f32x4 sB = {0.f, 0.f, 0.f, 0.f};
            sA = MFMA16(ka[0][0], qb0[nt], sA); sA = MFMA16(ka[0][1], qb1[nt], sA);
            sB = MFMA16(ka[1][0], qb0[nt], sB); sB = MFMA16(ka[1][1], qb1[nt], sB);

            float rowm = fmaxf(fmaxf(fmaxf(sA[0], sA[1]), fmaxf(sA[2], sA[3])),
                               fmaxf(fmaxf(sB[0], sB[1]), fmaxf(sB[2], sB[3])));
            rowm = fmaxf(rowm, __shfl_xor(rowm, 16, 64));
            rowm = fmaxf(rowm, __shfl_xor(rowm, 32, 64));

            const float mn = fmaxf(m[nt], rowm);
            const float al = __builtin_amdgcn_exp2f(m[nt] - mn);   // 0 first tile
            m[nt] = mn;

            const float p0 = __builtin_amdgcn_exp2f(sA[0] - mn);
            const float p1 = __builtin_amdgcn_exp2f(sA[1] - mn);
            const float p2 = __builtin_amdgcn_exp2f(sA[2] - mn);
            const float p3 = __builtin_amdgcn_exp2f(sA[3] - mn);
            const float p4 = __builtin_amdgcn_exp2f(sB[0] - mn);
            const float p5 = __builtin_amdgcn_exp2f(sB[1] - mn);
            const float p6 = __builtin_amdgcn_exp2f(sB[2] - mn);
            const float p7 = __builtin_amdgcn_exp2f(sB[3] - mn);
            float rs = ((p0 + p1) + (p2 + p3)) + ((p4 + p5) + (p6 + p7));
            rs += __shfl_xor(rs, 16, 64);
            rs += __shfl_xor(rs, 32, 64);
            l[nt] = l[nt] * al + rs;

            union { u32 u[4]; bf16x8 v; } pb;   // B-frag: k_mfma = quad*8+mt*4+r
            pb.u[0] = packbf(p0, p1);
            pb.u[1] = packbf(p2, p3);
            pb.u[2] = packbf(p4, p5);
            pb.u[3] = packbf(p6, p7);

#pragma unroll
            for (int dt = 0; dt < 4; ++dt) {
                o[dt][nt] *= al;
                o[dt][nt] = MFMA16(va[dt], pb.v, o[dt][nt]);
            }
        }
        __syncthreads();   // cur buffer free; next tile's DMA drained
    }

    // ---- split-K combine across the 4 waves ----
    if (quad == 0) {
#pragma unroll
        for (int nt = 0; nt < 4; ++nt) {
            mbuf[w * 64 + nt * 16 + col] = m[nt];
            lbuf[w * 64 + nt * 16 + col] = l[nt];
        }
    }
    __syncthreads();

    float scale[4];
#pragma unroll
    for (int nt = 0; nt < 4; ++nt) {
        const int qi = nt * 16 + col;
        const float m0 = mbuf[qi], m1 = mbuf[64 + qi], m2 = mbuf[128 + qi], m3 = mbuf[192 + qi];
        const float M = fmaxf(fmaxf(m0, m1), fmaxf(m2, m3));
        const float L = lbuf[qi]       * __builtin_amdgcn_exp2f(m0 - M)
                      + lbuf[64 + qi]  * __builtin_amdgcn_exp2f(m1 - M)
                      + lbuf[128 + qi] * __builtin_amdgcn_exp2f(m2 - M)
                      + lbuf[192 + qi] * __builtin_amdgcn_exp2f(m3 - M);
        scale[nt] = __builtin_amdgcn_exp2f(m[nt] - M) / L;
    }
    __syncthreads();   // mbuf/lbuf read done before slab writes (slabB overlaps lbuf? no; safety for slabA alias of K buf)
#pragma unroll
    for (int dt = 0; dt < 4; ++dt)
#pragma unroll
        for (int nt = 0; nt < 4; ++nt) o[dt][nt] *= scale[nt];

    // waves 0,2 write slabs; waves 1,3 accumulate; slab[q][d] pitch 68
    if (w == 0 || w == 2) {
        float* s = (w == 0) ? slabA : slabB;
#pragma unroll
        for (int dt = 0; dt < 4; ++dt)
#pragma unroll
            for (int nt = 0; nt < 4; ++nt)
                *(f32x4*)&s[(nt * 16 + col) * 68 + dt * 16 + quad * 4] = o[dt][nt];
    }
    __syncthreads();
    if (w == 1 || w == 3) {
        float* s = (w == 1) ? slabA : slabB;
#pragma unroll
        for (int dt = 0; dt < 4; ++dt)
#pragma unroll
            for (int nt = 0; nt < 4; ++nt) {
                f32x4* p = (f32x4*)&s[(nt * 16 + col) * 68 + dt * 16 + quad * 4];
                *p = *p + o[dt][nt];
            }
    }
    __syncthreads();

    // final coalesced store
    const int qr = tid >> 2, fq = tid & 3;
#pragma unroll
    for (int j = 0; j < 4; ++j) {
        const f32x4 a = *(const f32x4*)&slabA[qr * 68 + fq * 16 + j * 4];
        const f32x4 c = *(const f32x4*)&slabB[qr * 68 + fq * 16 + j * 4];
        *(f32x4*)&out[(size_t)(b * NS + q0 + qr) * ND + h * NDH + fq * 16 + j * 4] = a + c;
    }
}

extern "C" void kernel_launch(void* const* d_in, const int* in_sizes, int n_in,
                              void* d_out, int out_size, void* d_ws, size_t ws_size,
                              hipStream_t stream) {
    (void)in_sizes; (void)n_in; (void)out_size; (void)ws_size;
    const float* x  = (const float*)d_in[0];
    const float* wq = (const float*)d_in[1];
    const float* bq = (const float*)d_in[2];
    const float* wk = (const float*)d_in[3];
    const float* bk = (const float*)d_in[4];
    const float* wv = (const float*)d_in[5];
    const float* bv = (const float*)d_in[6];
    float* out = (float*)d_out;

    __bf16* qws  = (__bf16*)d_ws;
    __bf16* kws  = qws + (size_t)NB * NH * NS * NDH;
    __bf16* vtws = kws + (size_t)NB * NH * NS * NDH;

    dim3 pgrid(NS / 128, NH, NB);
    proj_kernel<<<pgrid, 256, 0, stream>>>(x, wq, bq, wk, bk, wv, bv, qws, kws, vtws);
    dim3 agrid(NS / 64, NH, NB);
    attn_kernel<<<agrid, 256, 0, stream>>>(qws, kws, vtws, out);
}